// Round 6
// baseline (411.401 us; speedup 1.0000x reference)
//
#include <hip/hip_runtime.h>
#include <hip/hip_bf16.h>

#define NF 100000
#define TM 64
#define NB 1563   // ceil(NF/TM) fact-blocks per relation

typedef __attribute__((ext_vector_type(8))) short bf16x8;
typedef __attribute__((ext_vector_type(4))) short bf16x4;
typedef __attribute__((ext_vector_type(4))) float f32x4;

__device__ __forceinline__ short bfs(float x) {
    union { __hip_bfloat16 h; short s; } u;
    u.h = __float2bfloat16(x);
    return u.s;
}

__device__ __forceinline__ float b2f(short s) {
    union { float f; unsigned u; } u;
    u.u = ((unsigned)(unsigned short)s) << 16;
    return u.f;
}

__device__ __forceinline__ bf16x8 cvt8(const float4 a, const float4 b) {
    bf16x8 r;
    r[0] = bfs(a.x); r[1] = bfs(a.y); r[2] = bfs(a.z); r[3] = bfs(a.w);
    r[4] = bfs(b.x); r[5] = bfs(b.y); r[6] = bfs(b.z); r[7] = bfs(b.w);
    return r;
}

__device__ __forceinline__ float mish_f(float v) {
    // mish(x) = x * (t^2+2t)/(t^2+2t+2), t=e^x; exact passthrough for v>20
    float t = __expf(v);
    float p = t * (t + 2.0f);
    float r = v * p * __builtin_amdgcn_rcpf(p + 2.0f);
    return (v > 20.0f) ? v : r;
}

// ---- fp32 -> bf16 pre-conversion ----
__global__ __launch_bounds__(256)
void cvt_emb(const float* __restrict__ in, __hip_bfloat16* __restrict__ out) {
    long e = ((long)blockIdx.x * 256 + threadIdx.x) * 8;
    const float4* s = (const float4*)(in + e);
    *(bf16x8*)(out + e) = cvt8(s[0], s[1]);
}

struct CvtW {
    const float* src[8];
    long pre[9];
};

__global__ __launch_bounds__(256)
void cvt_w(CvtW a, __hip_bfloat16* __restrict__ dst) {
    long e = ((long)blockIdx.x * 256 + threadIdx.x) * 8;
    if (e >= a.pre[8]) return;
    int k = 0;
    #pragma unroll
    for (int j = 0; j < 8; j++) if (e >= a.pre[j + 1]) k = j + 1;
    const float4* s = (const float4*)(a.src[k] + (e - a.pre[k]));
    *(bf16x8*)(dst + e) = cvt8(s[0], s[1]);
}

// ---- per-group body: gather -> GEMM1 -> mish -> GEMM2 -> residual -> store ----
// Wave tiling: 2 fact-halves x 2 col-halves (RT=2, CT=D/32). Swapped MFMA
// (A=weight frag, B=fact frag): C/D col(lane&15)=fact, row(kg*4+j)=4 consecutive
// output cols -> vector epilogues. Single LDS buffer; residual kept in VGPRs.
template<int D, int A, bool PRE>
__device__ __forceinline__ void group_body(
    int fb, int g,
    const void* __restrict__ embv, const int* __restrict__ idx,
    const void* __restrict__ wiv, const float* __restrict__ bi,
    const void* __restrict__ wov, const float* __restrict__ bo,
    float* __restrict__ out_msgs, float* __restrict__ out_idx,
    __hip_bfloat16* buf)
{
    constexpr int DP = D + 8;        // row stride: conflict-free ds_read_b128 groups
    constexpr int CT = D / 32;       // 16-col tiles per wave (covers D/2 cols)
    constexpr int KS = D / 32;       // K-steps
    constexpr int RC = D / 8;        // bf16x8 chunks per row

    const int tid  = threadIdx.x;
    const int lane = tid & 63;
    const int w    = tid >> 6;
    const int wm   = w & 1;          // fact half
    const int wn   = w >> 1;         // col half
    const int f0   = fb * TM;
    const long gFA = (long)g * NF * A;
    const int valid = min(TM, NF - f0);

    // ---- gather X rows into LDS (bf16), emit indices (f32) ----
    {
        const int* idx_g = idx + gFA + (long)f0 * A;
        #pragma unroll
        for (int c = tid; c < TM * RC; c += 256) {
            int r = c / RC;
            int i = (c - r * RC) * 8;
            bf16x8 v = (bf16x8)0;
            if (r < valid) {
                int node = idx_g[r * A + (i >> 6)];
                if constexpr (PRE) {
                    v = *(const bf16x8*)((const __hip_bfloat16*)embv + (long)node * 64 + (i & 63));
                } else {
                    const float4* s = (const float4*)((const float*)embv + (long)node * 64 + (i & 63));
                    v = cvt8(s[0], s[1]);
                }
            }
            *(bf16x8*)(buf + r * DP + i) = v;
        }
        if (tid < valid * A) out_idx[gFA + (long)f0 * A + tid] = (float)idx_g[tid];
    }
    __syncthreads();

    const int ar = lane & 15;
    const int kg = lane >> 4;
    const int fbase = wm * 32;
    const int cbase = wn * (D / 2);
    const long wbase = (long)g * D * D;

    f32x4 acc[2][CT];
    #pragma unroll
    for (int rt = 0; rt < 2; rt++)
        #pragma unroll
        for (int ct = 0; ct < CT; ct++) acc[rt][ct] = (f32x4)0.0f;

    // ---- GEMM1 ----
    #pragma unroll
    for (int ks = 0; ks < KS; ks++) {
        const int kk = ks * 32;
        bf16x8 xb0 = *(const bf16x8*)(buf + (fbase + ar) * DP + kk + kg * 8);
        bf16x8 xb1 = *(const bf16x8*)(buf + (fbase + 16 + ar) * DP + kk + kg * 8);
        #pragma unroll
        for (int ct = 0; ct < CT; ct++) {
            bf16x8 wf;
            const long wofs = wbase + (long)(cbase + ct * 16 + ar) * D + kk + kg * 8;
            if constexpr (PRE) wf = *(const bf16x8*)((const __hip_bfloat16*)wiv + wofs);
            else { const float4* bp = (const float4*)((const float*)wiv + wofs); wf = cvt8(bp[0], bp[1]); }
            acc[0][ct] = __builtin_amdgcn_mfma_f32_16x16x32_bf16(wf, xb0, acc[0][ct], 0, 0, 0);
            acc[1][ct] = __builtin_amdgcn_mfma_f32_16x16x32_bf16(wf, xb1, acc[1][ct], 0, 0, 0);
        }
    }

    // ---- snapshot residual X values this lane needs in epilogue 2 ----
    bf16x4 res[2][CT];
    #pragma unroll
    for (int ct = 0; ct < CT; ct++) {
        const int cb = cbase + ct * 16 + kg * 4;
        #pragma unroll
        for (int rt = 0; rt < 2; rt++)
            res[rt][ct] = *(const bf16x4*)(buf + (fbase + rt * 16 + ar) * DP + cb);
    }
    __syncthreads();   // all X reads done before H overwrites buf

    // ---- epilogue 1: bias + mish -> buf (H) ----
    #pragma unroll
    for (int ct = 0; ct < CT; ct++) {
        const int cb = cbase + ct * 16 + kg * 4;
        const float4 bi4 = *(const float4*)(bi + g * D + cb);
        #pragma unroll
        for (int rt = 0; rt < 2; rt++) {
            bf16x4 hv;
            hv[0] = bfs(mish_f(acc[rt][ct][0] + bi4.x));
            hv[1] = bfs(mish_f(acc[rt][ct][1] + bi4.y));
            hv[2] = bfs(mish_f(acc[rt][ct][2] + bi4.z));
            hv[3] = bfs(mish_f(acc[rt][ct][3] + bi4.w));
            *(bf16x4*)(buf + (fbase + rt * 16 + ar) * DP + cb) = hv;
        }
    }
    __syncthreads();

    // ---- GEMM2 ----
    #pragma unroll
    for (int rt = 0; rt < 2; rt++)
        #pragma unroll
        for (int ct = 0; ct < CT; ct++) acc[rt][ct] = (f32x4)0.0f;

    #pragma unroll
    for (int ks = 0; ks < KS; ks++) {
        const int kk = ks * 32;
        bf16x8 hb0 = *(const bf16x8*)(buf + (fbase + ar) * DP + kk + kg * 8);
        bf16x8 hb1 = *(const bf16x8*)(buf + (fbase + 16 + ar) * DP + kk + kg * 8);
        #pragma unroll
        for (int ct = 0; ct < CT; ct++) {
            bf16x8 wf;
            const long wofs = wbase + (long)(cbase + ct * 16 + ar) * D + kk + kg * 8;
            if constexpr (PRE) wf = *(const bf16x8*)((const __hip_bfloat16*)wov + wofs);
            else { const float4* bp = (const float4*)((const float*)wov + wofs); wf = cvt8(bp[0], bp[1]); }
            acc[0][ct] = __builtin_amdgcn_mfma_f32_16x16x32_bf16(wf, hb0, acc[0][ct], 0, 0, 0);
            acc[1][ct] = __builtin_amdgcn_mfma_f32_16x16x32_bf16(wf, hb1, acc[1][ct], 0, 0, 0);
        }
    }

    // ---- epilogue 2: bias + residual(regs), float4 stores ----
    {
        float* ob = out_msgs + (gFA + (long)f0 * A) * 64;
        #pragma unroll
        for (int ct = 0; ct < CT; ct++) {
            const int cb = cbase + ct * 16 + kg * 4;
            const float4 bo4 = *(const float4*)(bo + g * D + cb);
            #pragma unroll
            for (int rt = 0; rt < 2; rt++) {
                const int r = fbase + rt * 16 + ar;
                float4 o;
                o.x = acc[rt][ct][0] + bo4.x + b2f(res[rt][ct][0]);
                o.y = acc[rt][ct][1] + bo4.y + b2f(res[rt][ct][1]);
                o.z = acc[rt][ct][2] + bo4.z + b2f(res[rt][ct][2]);
                o.w = acc[rt][ct][3] + bo4.w + b2f(res[rt][ct][3]);
                if (r < valid) *(float4*)(ob + (long)r * D + cb) = o;
            }
        }
    }
}

struct KArgs {
    const void* emb;
    const int* idx[4];
    const void* wi[4]; const float* bi[4];
    const void* wo[4]; const float* bo[4];
    float* om[4]; float* oi[4];
};

// Merged kernel: big-D ranges first for better tail behavior.
template<bool PRE>
__global__ __launch_bounds__(256, 3)
void fused_kernel(KArgs a) {
    __shared__ __hip_bfloat16 buf[TM * 264];   // 33.8 KB, sized for D=256 (DP=264)
    const int b = blockIdx.x;
    if (b < NB) {
        group_body<256, 4, PRE>(b, 0, a.emb, a.idx[3], a.wi[3], a.bi[3], a.wo[3], a.bo[3], a.om[3], a.oi[3], buf);
    } else if (b < NB * 3) {
        int r = b - NB;
        group_body<192, 3, PRE>(r % NB, r / NB, a.emb, a.idx[2], a.wi[2], a.bi[2], a.wo[2], a.bo[2], a.om[2], a.oi[2], buf);
    } else if (b < NB * 6) {
        int r = b - NB * 3;
        group_body<128, 2, PRE>(r % NB, r / NB, a.emb, a.idx[1], a.wi[1], a.bi[1], a.wo[1], a.bo[1], a.om[1], a.oi[1], buf);
    } else {
        int r = b - NB * 6;
        group_body<64, 1, PRE>(r % NB, r / NB, a.emb, a.idx[0], a.wi[0], a.bi[0], a.wo[0], a.bo[0], a.om[0], a.oi[0], buf);
    }
}

extern "C" void kernel_launch(void* const* d_in, const int* in_sizes, int n_in,
                              void* d_out, int out_size, void* d_ws, size_t ws_size,
                              hipStream_t stream) {
    const float* emb_f = (const float*)d_in[0];
    const int Gs[4] = {2, 3, 2, 1};
    const int Ds[4] = {64, 128, 192, 256};

    KArgs a;
    const float* wi_f[4]; const float* wo_f[4];
    for (int k = 0; k < 4; k++) {
        a.idx[k] = (const int*)d_in[1 + 5 * k];
        wi_f[k]  = (const float*)d_in[2 + 5 * k];
        a.bi[k]  = (const float*)d_in[3 + 5 * k];
        wo_f[k]  = (const float*)d_in[4 + 5 * k];
        a.bo[k]  = (const float*)d_in[5 + 5 * k];
    }

    float* out = (float*)d_out;
    const long MSG_ELEMS = 115200000L;               // 1.8M rows * 64 (f32)
    const long rowOff[4] = {0, 200000, 800000, 1400000};
    for (int k = 0; k < 4; k++) {
        a.om[k] = out + rowOff[k] * 64;
        a.oi[k] = out + MSG_ELEMS + rowOff[k];
    }

    const long EMB_ELEMS = 6400000L;                 // 100000*64
    long wPre[9]; wPre[0] = 0;
    for (int k = 0; k < 4; k++) {
        long we = (long)Gs[k] * Ds[k] * Ds[k];
        wPre[2 * k + 1] = wPre[2 * k] + we;
        wPre[2 * k + 2] = wPre[2 * k + 1] + we;
    }
    const long NEED = (EMB_ELEMS + wPre[8]) * 2;

    if (ws_size >= (size_t)NEED) {
        __hip_bfloat16* emb_b = (__hip_bfloat16*)d_ws;
        __hip_bfloat16* w_b   = emb_b + EMB_ELEMS;

        cvt_emb<<<dim3(EMB_ELEMS / 8 / 256), dim3(256), 0, stream>>>(emb_f, emb_b);
        CvtW cw;
        for (int k = 0; k < 4; k++) { cw.src[2 * k] = wi_f[k]; cw.src[2 * k + 1] = wo_f[k]; }
        for (int j = 0; j < 9; j++) cw.pre[j] = wPre[j];
        cvt_w<<<dim3((wPre[8] / 8 + 255) / 256), dim3(256), 0, stream>>>(cw, w_b);

        a.emb = emb_b;
        for (int k = 0; k < 4; k++) {
            a.wi[k] = w_b + wPre[2 * k];
            a.wo[k] = w_b + wPre[2 * k + 1];
        }
        fused_kernel<true><<<dim3(NB * 8), dim3(256), 0, stream>>>(a);
    } else {
        a.emb = emb_f;
        for (int k = 0; k < 4; k++) { a.wi[k] = wi_f[k]; a.wo[k] = wo_f[k]; }
        fused_kernel<false><<<dim3(NB * 8), dim3(256), 0, stream>>>(a);
    }
}

// Round 7
// 357.393 us; speedup vs baseline: 1.1511x; 1.1511x over previous
//
#include <hip/hip_runtime.h>
#include <hip/hip_bf16.h>

#define NF 100000
#define TM 64
#define NB 1563   // ceil(NF/TM)

typedef __attribute__((ext_vector_type(8))) short bf16x8;
typedef __attribute__((ext_vector_type(4))) short bf16x4;
typedef __attribute__((ext_vector_type(4))) float f32x4;

__device__ __forceinline__ short bfs(float x) {
    union { __hip_bfloat16 h; short s; } u;
    u.h = __float2bfloat16(x);
    return u.s;
}

__device__ __forceinline__ float b2f(short s) {
    union { float f; unsigned u; } u;
    u.u = ((unsigned)(unsigned short)s) << 16;
    return u.f;
}

__device__ __forceinline__ bf16x8 cvt8(const float4 a, const float4 b) {
    bf16x8 r;
    r[0] = bfs(a.x); r[1] = bfs(a.y); r[2] = bfs(a.z); r[3] = bfs(a.w);
    r[4] = bfs(b.x); r[5] = bfs(b.y); r[6] = bfs(b.z); r[7] = bfs(b.w);
    return r;
}

__device__ __forceinline__ float mish_f(float v) {
    // mish(x) = x * (t^2+2t)/(t^2+2t+2), t=e^x; exact passthrough for v>20
    float t = __expf(v);
    float p = t * (t + 2.0f);
    float r = v * p * __builtin_amdgcn_rcpf(p + 2.0f);
    return (v > 20.0f) ? v : r;
}

// ---- fp32 -> bf16 pre-conversion ----
__global__ __launch_bounds__(256)
void cvt_emb(const float* __restrict__ in, __hip_bfloat16* __restrict__ out) {
    long e = ((long)blockIdx.x * 256 + threadIdx.x) * 8;
    const float4* s = (const float4*)(in + e);
    *(bf16x8*)(out + e) = cvt8(s[0], s[1]);
}

struct CvtW {
    const float* src[8];
    long pre[9];
};

__global__ __launch_bounds__(256)
void cvt_w(CvtW a, __hip_bfloat16* __restrict__ dst) {
    long e = ((long)blockIdx.x * 256 + threadIdx.x) * 8;
    if (e >= a.pre[8]) return;
    int k = 0;
    #pragma unroll
    for (int j = 0; j < 8; j++) if (e >= a.pre[j + 1]) k = j + 1;
    const float4* s = (const float4*)(a.src[k] + (e - a.pre[k]));
    *(bf16x8*)(dst + e) = cvt8(s[0], s[1]);
}

// ---- per-group fused kernel ----
// TM=64 facts/block, 4 waves, each wave: all 64 facts x D/4 cols (RT=4, CT=D/64)
// -> 0.25 global weight-loads per MFMA. Single LDS buffer (X then H); the
// residual X values each lane needs in epilogue 2 are snapshotted to VGPRs.
// Swapped MFMA (A=weight frag, B=fact frag): C/D col(lane&15)=fact row,
// row(kg*4+j)=4 consecutive output cols -> vector epilogues, float4 stores.
template<int D, int A, bool PRE, int MINW>
__global__ __launch_bounds__(256, MINW)
void msg_kernel(const void* __restrict__ embv,
                const int* __restrict__ idx,
                const void* __restrict__ wiv, const float* __restrict__ bi,
                const void* __restrict__ wov, const float* __restrict__ bo,
                float* __restrict__ out_msgs, float* __restrict__ out_idx)
{
    constexpr int DP = D + 8;
    constexpr int CT = D / 64;
    constexpr int KS = D / 32;
    constexpr int RC = D / 8;
    __shared__ __hip_bfloat16 buf[TM][DP];

    const int g    = blockIdx.y;
    const int f0   = blockIdx.x * TM;
    const int tid  = threadIdx.x;
    const int lane = tid & 63;
    const int w    = tid >> 6;
    const long gFA = (long)g * NF * A;
    const int valid = min(TM, NF - f0);

    // ---- gather X rows into LDS (bf16), emit indices (f32) ----
    {
        const int* idx_g = idx + gFA + (long)f0 * A;
        #pragma unroll
        for (int c = tid; c < TM * RC; c += 256) {
            int r = c / RC;
            int i = (c - r * RC) * 8;
            bf16x8 v = (bf16x8)0;
            if (r < valid) {
                int node = idx_g[r * A + (i >> 6)];
                if constexpr (PRE) {
                    v = *(const bf16x8*)((const __hip_bfloat16*)embv + (long)node * 64 + (i & 63));
                } else {
                    const float4* s = (const float4*)((const float*)embv + (long)node * 64 + (i & 63));
                    v = cvt8(s[0], s[1]);
                }
            }
            *(bf16x8*)(&buf[r][i]) = v;
        }
        if (tid < valid * A) out_idx[gFA + (long)f0 * A + tid] = (float)idx_g[tid];
    }
    __syncthreads();

    const int ar = lane & 15;
    const int kg = lane >> 4;
    const int c0 = w * (D / 4);
    const long wbase = (long)g * D * D;

    f32x4 acc[4][CT];
    #pragma unroll
    for (int rt = 0; rt < 4; rt++)
        #pragma unroll
        for (int ct = 0; ct < CT; ct++) acc[rt][ct] = (f32x4)0.0f;

    // ---- GEMM1: Wi x X^T ----
    #pragma unroll
    for (int ks = 0; ks < KS; ks++) {
        const int kk = ks * 32;
        bf16x8 xb[4];
        #pragma unroll
        for (int rt = 0; rt < 4; rt++) xb[rt] = *(const bf16x8*)(&buf[rt * 16 + ar][kk + kg * 8]);
        #pragma unroll
        for (int ct = 0; ct < CT; ct++) {
            bf16x8 wf;
            const long wofs = wbase + (long)(c0 + ct * 16 + ar) * D + kk + kg * 8;
            if constexpr (PRE) wf = *(const bf16x8*)((const __hip_bfloat16*)wiv + wofs);
            else { const float4* bp = (const float4*)((const float*)wiv + wofs); wf = cvt8(bp[0], bp[1]); }
            #pragma unroll
            for (int rt = 0; rt < 4; rt++)
                acc[rt][ct] = __builtin_amdgcn_mfma_f32_16x16x32_bf16(wf, xb[rt], acc[rt][ct], 0, 0, 0);
        }
    }

    // ---- snapshot residual X values (per-lane 4 cols x 4 row-tiles) ----
    bf16x4 res[4][CT];
    #pragma unroll
    for (int ct = 0; ct < CT; ct++) {
        const int cb = c0 + ct * 16 + kg * 4;
        #pragma unroll
        for (int rt = 0; rt < 4; rt++)
            res[rt][ct] = *(const bf16x4*)(&buf[rt * 16 + ar][cb]);
    }
    __syncthreads();   // all X reads complete before H overwrites buf

    // ---- epilogue 1: bias + mish -> buf (H) ----
    #pragma unroll
    for (int ct = 0; ct < CT; ct++) {
        const int cb = c0 + ct * 16 + kg * 4;
        const float4 bi4 = *(const float4*)(bi + g * D + cb);
        #pragma unroll
        for (int rt = 0; rt < 4; rt++) {
            bf16x4 hv;
            hv[0] = bfs(mish_f(acc[rt][ct][0] + bi4.x));
            hv[1] = bfs(mish_f(acc[rt][ct][1] + bi4.y));
            hv[2] = bfs(mish_f(acc[rt][ct][2] + bi4.z));
            hv[3] = bfs(mish_f(acc[rt][ct][3] + bi4.w));
            *(bf16x4*)(&buf[rt * 16 + ar][cb]) = hv;
        }
    }
    __syncthreads();

    // ---- GEMM2: Wo x H^T ----
    #pragma unroll
    for (int rt = 0; rt < 4; rt++)
        #pragma unroll
        for (int ct = 0; ct < CT; ct++) acc[rt][ct] = (f32x4)0.0f;

    #pragma unroll
    for (int ks = 0; ks < KS; ks++) {
        const int kk = ks * 32;
        bf16x8 hb[4];
        #pragma unroll
        for (int rt = 0; rt < 4; rt++) hb[rt] = *(const bf16x8*)(&buf[rt * 16 + ar][kk + kg * 8]);
        #pragma unroll
        for (int ct = 0; ct < CT; ct++) {
            bf16x8 wf;
            const long wofs = wbase + (long)(c0 + ct * 16 + ar) * D + kk + kg * 8;
            if constexpr (PRE) wf = *(const bf16x8*)((const __hip_bfloat16*)wov + wofs);
            else { const float4* bp = (const float4*)((const float*)wov + wofs); wf = cvt8(bp[0], bp[1]); }
            #pragma unroll
            for (int rt = 0; rt < 4; rt++)
                acc[rt][ct] = __builtin_amdgcn_mfma_f32_16x16x32_bf16(wf, hb[rt], acc[rt][ct], 0, 0, 0);
        }
    }

    // ---- epilogue 2: bias + residual(regs), float4 stores ----
    {
        float* ob = out_msgs + (gFA + (long)f0 * A) * 64;
        #pragma unroll
        for (int ct = 0; ct < CT; ct++) {
            const int cb = c0 + ct * 16 + kg * 4;
            const float4 bo4 = *(const float4*)(bo + g * D + cb);
            #pragma unroll
            for (int rt = 0; rt < 4; rt++) {
                const int r = rt * 16 + ar;
                float4 o;
                o.x = acc[rt][ct][0] + bo4.x + b2f(res[rt][ct][0]);
                o.y = acc[rt][ct][1] + bo4.y + b2f(res[rt][ct][1]);
                o.z = acc[rt][ct][2] + bo4.z + b2f(res[rt][ct][2]);
                o.w = acc[rt][ct][3] + bo4.w + b2f(res[rt][ct][3]);
                if (r < valid) *(float4*)(ob + (long)r * D + cb) = o;
            }
        }
    }
}

extern "C" void kernel_launch(void* const* d_in, const int* in_sizes, int n_in,
                              void* d_out, int out_size, void* d_ws, size_t ws_size,
                              hipStream_t stream) {
    const float* emb_f = (const float*)d_in[0];
    const int Gs[4] = {2, 3, 2, 1};
    const int Ds[4] = {64, 128, 192, 256};

    const int*   idx_a[4];
    const float *wi_f[4], *bi_f[4], *wo_f[4], *bo_f[4];
    for (int k = 0; k < 4; k++) {
        idx_a[k] = (const int*)d_in[1 + 5 * k];
        wi_f[k]  = (const float*)d_in[2 + 5 * k];
        bi_f[k]  = (const float*)d_in[3 + 5 * k];
        wo_f[k]  = (const float*)d_in[4 + 5 * k];
        bo_f[k]  = (const float*)d_in[5 + 5 * k];
    }

    float* out = (float*)d_out;
    const long MSG_ELEMS = 115200000L;
    const long rowOff[4] = {0, 200000, 800000, 1400000};
    float* om[4]; float* oi[4];
    for (int k = 0; k < 4; k++) {
        om[k] = out + rowOff[k] * 64;
        oi[k] = out + MSG_ELEMS + rowOff[k];
    }

    const long EMB_ELEMS = 6400000L;
    long wPre[9]; wPre[0] = 0;
    for (int k = 0; k < 4; k++) {
        long we = (long)Gs[k] * Ds[k] * Ds[k];
        wPre[2 * k + 1] = wPre[2 * k] + we;
        wPre[2 * k + 2] = wPre[2 * k + 1] + we;
    }
    const long NEED = (EMB_ELEMS + wPre[8]) * 2;

    if (ws_size >= (size_t)NEED) {
        __hip_bfloat16* emb_b = (__hip_bfloat16*)d_ws;
        __hip_bfloat16* w_b   = emb_b + EMB_ELEMS;

        cvt_emb<<<dim3(EMB_ELEMS / 8 / 256), dim3(256), 0, stream>>>(emb_f, emb_b);
        CvtW cw;
        for (int k = 0; k < 4; k++) { cw.src[2 * k] = wi_f[k]; cw.src[2 * k + 1] = wo_f[k]; }
        for (int j = 0; j < 9; j++) cw.pre[j] = wPre[j];
        cvt_w<<<dim3((wPre[8] / 8 + 255) / 256), dim3(256), 0, stream>>>(cw, w_b);

        const __hip_bfloat16 *wi_b[4], *wo_b[4];
        for (int k = 0; k < 4; k++) { wi_b[k] = w_b + wPre[2 * k]; wo_b[k] = w_b + wPre[2 * k + 1]; }

        msg_kernel<64, 1, true, 4><<<dim3(NB, 2), 256, 0, stream>>>(
            emb_b, idx_a[0], wi_b[0], bi_f[0], wo_b[0], bo_f[0], om[0], oi[0]);
        msg_kernel<128, 2, true, 4><<<dim3(NB, 3), 256, 0, stream>>>(
            emb_b, idx_a[1], wi_b[1], bi_f[1], wo_b[1], bo_f[1], om[1], oi[1]);
        msg_kernel<192, 3, true, 4><<<dim3(NB, 2), 256, 0, stream>>>(
            emb_b, idx_a[2], wi_b[2], bi_f[2], wo_b[2], bo_f[2], om[2], oi[2]);
        msg_kernel<256, 4, true, 3><<<dim3(NB, 1), 256, 0, stream>>>(
            emb_b, idx_a[3], wi_b[3], bi_f[3], wo_b[3], bo_f[3], om[3], oi[3]);
    } else {
        msg_kernel<64, 1, false, 4><<<dim3(NB, 2), 256, 0, stream>>>(
            emb_f, idx_a[0], wi_f[0], bi_f[0], wo_f[0], bo_f[0], om[0], oi[0]);
        msg_kernel<128, 2, false, 4><<<dim3(NB, 3), 256, 0, stream>>>(
            emb_f, idx_a[1], wi_f[1], bi_f[1], wo_f[1], bo_f[1], om[1], oi[1]);
        msg_kernel<192, 3, false, 4><<<dim3(NB, 2), 256, 0, stream>>>(
            emb_f, idx_a[2], wi_f[2], bi_f[2], wo_f[2], bo_f[2], om[2], oi[2]);
        msg_kernel<256, 4, false, 3><<<dim3(NB, 1), 256, 0, stream>>>(
            emb_f, idx_a[3], wi_f[3], bi_f[3], wo_f[3], bo_f[3], om[3], oi[3]);
    }
}